// Round 14
// baseline (294.755 us; speedup 1.0000x reference)
//
#include <hip/hip_runtime.h>
#include <hip/hip_bf16.h>

#define NEMB  4096
#define DIM   128
#define NROWS 32768
#define MARGIN 3.5e-4f   // >= 5x approx-error bound; validated r5-r8 (+1e-9 fold term)
#define RPB   128        // rows per block -> grid 256 = 1 block/CU
#define CHUNK 128        // codes per K-loop iteration
#define NITER 32         // NEMB/CHUNK

typedef _Float16 half8  __attribute__((ext_vector_type(8)));
typedef _Float16 half4v __attribute__((ext_vector_type(4)));
typedef _Float16 half2v __attribute__((ext_vector_type(2)));
typedef float    float16v __attribute__((ext_vector_type(16)));

typedef const __attribute__((address_space(1))) void* gas_ptr;
typedef __attribute__((address_space(3))) void*       las_ptr;

__device__ __forceinline__ void gload16(const void* g, void* l) {
    __builtin_amdgcn_global_load_lds((gas_ptr)g, (las_ptr)l, 16, 0, 0);
}

__device__ __forceinline__ half2v hmin2(half2v a, half2v b) {
    half2v r;
    r.x = (a.x < b.x) ? a.x : b.x;
    r.y = (a.y < b.y) ? a.y : b.y;
    return r;
}

// Peel the first flagged group from the 4 wave-uniform ballot masks.
// j=0/1: word 2l half 0/1; j=2/3: word 2l+1 half 0/1.  g = 2*((wsl-lr)&127)+half.
// Sets G=-1 when all masks empty.  (Same index math as the R12 j-loop; the
// (d,c)-lexicographic min is order-independent, so peel order is semantics-free.)
#define PEEL(G) \
    if (m0) { const int l = __builtin_ctzll(m0); m0 &= m0 - 1; \
              G = 2 * ((2 * l - lr) & 127); } \
    else if (m1) { const int l = __builtin_ctzll(m1); m1 &= m1 - 1; \
              G = 2 * ((2 * l - lr) & 127) + 1; } \
    else if (m2) { const int l = __builtin_ctzll(m2); m2 &= m2 - 1; \
              G = 2 * ((2 * l + 1 - lr) & 127); } \
    else if (m3) { const int l = __builtin_ctzll(m3); m3 &= m3 - 1; \
              G = 2 * ((2 * l + 1 - lr) & 127) + 1; } \
    else G = -1;

// ---------------- K1: W -> fp16 (scale 2^16) fragment-major + ||w||^2 + swwh ----
__launch_bounds__(256)
__global__ void k_prep(const float* __restrict__ W, _Float16* __restrict__ Wh2,
                       float* __restrict__ sww, _Float16* __restrict__ swwh,
                       double* __restrict__ dsum, int* __restrict__ cnt) {
    const int b = blockIdx.x;               // 512 blocks, 8 rows each
    const int t = threadIdx.x;
    const int rbase = b * 8;

    if (b == 0 && t == 0) { *dsum = 0.0; *cnt = 0; }   // loss accumulators

    const int i4 = rbase * 32 + t;
    const float4 v = ((const float4*)W)[i4];
    const int r  = i4 >> 5;
    const int k0 = (i4 & 31) * 4;
    const int s  = r >> 5, cs = r & 31, c = k0 >> 4, h2 = (k0 >> 3) & 1, j0 = k0 & 7;
    half4v hv = { (_Float16)(v.x * 65536.0f), (_Float16)(v.y * 65536.0f),
                  (_Float16)(v.z * 65536.0f), (_Float16)(v.w * 65536.0f) };
    *(half4v*)(Wh2 + (s * 8 + c) * 512 + (h2 * 32 + cs) * 8 + j0) = hv;

    if (t < 64) {   // numpy-pairwise ||w||^2 (exact fp32 semantics, validated r3-r8)
        const int row = rbase + (t >> 3);
        const int j   = t & 7;
        const float* p = W + (size_t)row * DIM + j;
        float vv = p[0];
        float rr = __fmul_rn(vv, vv);
        #pragma unroll
        for (int q = 1; q < 16; ++q) { vv = p[q * 8]; rr = __fadd_rn(rr, __fmul_rn(vv, vv)); }
        float o = __shfl_xor(rr, 1, 64); rr = __fadd_rn(rr, o);
        o = __shfl_xor(rr, 2, 64); rr = __fadd_rn(rr, o);
        o = __shfl_xor(rr, 4, 64); rr = __fadd_rn(rr, o);
        if (j == 0) {
            sww[row]  = rr;
            swwh[row] = (_Float16)(rr * 32768.0f);   // sww*2^15, |err| ~ sww*2^-11
        }
    }
}

// ---------------- K2: R12 scan + refine front-half batching + paired eval (R22) ----
// Scan: R12 (zero16 C-operand, persistent ax, hoisted prologue DMA) -- untouched.
// Refine: (a) gbuf reads + 6-stage min-reduce + sxr shfls batched 8-wide (the
// SAFE subset of R11; batched argmin/gather/stores that regressed stay per-row);
// (b) candidate eval peels up to 2 groups per pass -- both W-quarter loads issue
// together, two independent fmaf/shfl chains.  (d,c)-min is order-independent
// -> outputs bit-identical to R12.
__global__ __launch_bounds__(1024, 4)
void k_main(const float* __restrict__ x, const _Float16* __restrict__ Wh2,
            const float* __restrict__ W, const float* __restrict__ sww,
            const _Float16* __restrict__ swwh,
            float* __restrict__ out0, float* __restrict__ out1,
            float* __restrict__ out_idx, double* __restrict__ dsum,
            int* __restrict__ cnt, float* __restrict__ out_loss) {
    __shared__ __align__(16) _Float16 sA[2 * CHUNK * DIM];   // 64 KB dbuf / x-cache
    __shared__ _Float16 gbuf[RPB * 256];       // 64 KB group minima (swizzled)
    __shared__ float ssw[NEMB];                // 16 KB sww copy (refine only)
    __shared__ _Float16 swwh_lds[NEMB];        // 8 KB sww*2^15 fp16 (scan fold)
    __shared__ float red16[16];                // block loss partials

    const int tid  = threadIdx.x;
    const int wv   = tid >> 6;      // 0..15
    const int lane = tid & 63;
    const int l31  = lane & 31;
    const int h    = lane >> 5;
    const int r0   = blockIdx.x * RPB;
    const int mt   = wv & 3;        // 32-code slab within chunk
    const int np   = wv >> 2;       // ntile 0..3 (rows np*32..np*32+31)

    // prologue DMA first: chunk `start` -> buffer 0; latency hides under staging
    const int start = (blockIdx.x >> 3) & 31;
    {
        const char* src = (const char*)Wh2 + (size_t)start * (CHUNK * DIM * 2);
        #pragma unroll
        for (int r = 0; r < 2; ++r)
            gload16(src + wv * 2048 + r * 1024 + lane * 16, (char*)sA + wv * 2048 + r * 1024);
    }

    ((float4*)ssw)[tid] = ((const float4*)sww)[tid];
    if (tid < 512) ((float4*)swwh_lds)[tid] = ((const float4*)swwh)[tid];

    // B fragments: x rows of ntile np -> fp16 regs, B[n=lane&31][k=h*8+j] per 16-k chunk
    half8 bfr[8];
    {
        const float* xr = x + (size_t)(r0 + np * 32 + l31) * DIM + h * 8;
        #pragma unroll
        for (int c = 0; c < 8; ++c) {
            const float4 u0 = *(const float4*)(xr + c * 16);
            const float4 u1 = *(const float4*)(xr + c * 16 + 4);
            bfr[c] = (half8){ (_Float16)u0.x, (_Float16)u0.y, (_Float16)u0.z, (_Float16)u0.w,
                              (_Float16)u1.x, (_Float16)u1.y, (_Float16)u1.z, (_Float16)u1.w };
        }
    }

    // B_extra: B[row][k=0] = -1  (k=0 lives at h==0, j==0)
    half8 bx2 = (_Float16)0.0f;
    if (h == 0) bx2[0] = (_Float16)-1.0f;

    // loop-invariant zero accumulator (C operand of the first MFMA)
    float16v zero16;
    #pragma unroll
    for (int i = 0; i < 16; ++i) zero16[i] = 0.f;

    // ax: high regs zeroed once; only element 0 rewritten per iteration
    half8 ax = (_Float16)0.0f;

    // sxx (numpy-pairwise exact) for this wave's 8 refine rows, kept in regs
    float sxx_reg;
    {
        const float* ps = x + (size_t)(r0 + wv * 8 + (lane >> 3)) * DIM + (lane & 7);
        float vv = ps[0];
        float rr = __fmul_rn(vv, vv);
        #pragma unroll
        for (int q = 1; q < 16; ++q) { vv = ps[q * 8]; rr = __fadd_rn(rr, __fmul_rn(vv, vv)); }
        float o = __shfl_xor(rr, 1, 64); rr = __fadd_rn(rr, o);
        o = __shfl_xor(rr, 2, 64); rr = __fadd_rn(rr, o);
        o = __shfl_xor(rr, 4, 64); rr = __fadd_rn(rr, o);
        sxx_reg = rr;
    }

    for (int it = 0; it < NITER; ++it) {
        __syncthreads();   // drains DMA issued one full iteration ago
        if (it + 1 < NITER) {
            const int nc = (start + it + 1) & (NITER - 1);
            const char* src = (const char*)Wh2 + (size_t)nc * (CHUNK * DIM * 2);
            char* dst = (char*)sA + ((it + 1) & 1) * (CHUNK * DIM * 2);
            #pragma unroll
            for (int r = 0; r < 2; ++r)
                gload16(src + wv * 2048 + r * 1024 + lane * 16, dst + wv * 2048 + r * 1024);
        }
        const int cb = (start + it) & (NITER - 1);
        const int s  = cb * 4 + mt;   // global 32-code slab [0,128)

        // A_extra elem 0: swwh[code] on h==0 lanes (other 7 halfs stay 0)
        ax[0] = (h == 0) ? swwh_lds[s * 32 + l31] : (_Float16)0.0f;

        const _Float16* curb = sA + (it & 1) * (CHUNK * DIM);

        // first MFMA consumes zero16 as C (no acc re-init), then accumulate
        float16v acc;
        {
            const half8 a0 = *(const half8*)(curb + (mt * 8 + 0) * 512 + lane * 8);
            acc = __builtin_amdgcn_mfma_f32_32x32x16_f16(a0, bfr[0], zero16, 0, 0, 0);
        }
        #pragma unroll
        for (int c = 1; c < 8; ++c) {
            const half8 a = *(const half8*)(curb + (mt * 8 + c) * 512 + lane * 8);
            acc = __builtin_amdgcn_mfma_f32_32x32x16_f16(a, bfr[c], acc, 0, 0, 0);
        }
        // 9th MFMA: acc' = 2^16 x.w - 2^15 sww
        acc = __builtin_amdgcn_mfma_f32_32x32x16_f16(ax, bx2, acc, 0, 0, 0);

        // epilogue: group min = -2^-15 * max(acc'); max exact, scale exact
        const float mx0 = fmaxf(fmaxf(fmaxf(acc[0], acc[1]), fmaxf(acc[2], acc[3])),
                                fmaxf(fmaxf(acc[4], acc[5]), fmaxf(acc[6], acc[7])));
        const float mx1 = fmaxf(fmaxf(fmaxf(acc[8], acc[9]), fmaxf(acc[10], acc[11])),
                                fmaxf(fmaxf(acc[12], acc[13]), fmaxf(acc[14], acc[15])));
        const float g0 = mx0 * -0x1p-15f;
        const float g1 = mx1 * -0x1p-15f;
        union { half2v h2; int u; } cu, ot;
        cu.h2.x = (_Float16)g0; cu.h2.y = (_Float16)g1;   // groups 2s, 2s+1
        ot.u = __shfl_xor(cu.u, 32, 64);
        cu.h2 = hmin2(cu.h2, ot.h2);
        if (h == 0) {
            const int row = np * 32 + l31;                // local row
            const int ws  = (s + row) & 127;              // swizzled word slot
            ((int*)gbuf)[row * 128 + ws] = cu.u;
        }
    }

    __syncthreads();   // scan complete; sA (DMA buffer) now dead

    // ---- refill sA with the block's x rows (64 KB fp32, coalesced) ----
    {
        float4* sAf4 = (float4*)sA;
        const float4* xg4 = (const float4*)(x + (size_t)r0 * DIM);
        #pragma unroll
        for (int i = 0; i < 4; ++i) sAf4[tid + i * 1024] = xg4[tid + i * 1024];
    }
    __syncthreads();
    const float* sAf = (const float*)sA;

    // ---- R22 refine: batched front-half + paired candidate eval ----
    const int cig = lane >> 2;
    const int kp  = lane & 3;

    // (a) batched gbuf reads (8 ds_read_b64, one wait) + min-reduce + sxr
    int2 gw[8];
    #pragma unroll
    for (int t = 0; t < 8; ++t)
        gw[t] = *(const int2*)((const char*)gbuf + (wv * 8 + t) * 512 + lane * 8);
    float m_[8];
    #pragma unroll
    for (int t = 0; t < 8; ++t) {
        union { half2v h2; int u; } pa, pb;
        pa.u = gw[t].x; pb.u = gw[t].y;
        m_[t] = fminf(fminf((float)pa.h2.x, (float)pa.h2.y),
                      fminf((float)pb.h2.x, (float)pb.h2.y));
    }
    #pragma unroll
    for (int off = 1; off < 64; off <<= 1) {
        #pragma unroll
        for (int t = 0; t < 8; ++t) m_[t] = fminf(m_[t], __shfl_xor(m_[t], off, 64));
    }
    float sxr[8];
    #pragma unroll
    for (int t = 0; t < 8; ++t) sxr[t] = __shfl(sxx_reg, t * 8, 64);

    float p_acc = 0.f;
    for (int t = 0; t < 8; ++t) {
        const int lr  = wv * 8 + t;
        const int row = r0 + lr;

        union { half2v h2; int u; } pa, pb;
        pa.u = gw[t].x; pb.u = gw[t].y;
        const float v0 = (float)pa.h2.x, v1 = (float)pa.h2.y;
        const float v2 = (float)pb.h2.x, v3 = (float)pb.h2.y;
        const float thr = m_[t] + MARGIN;
        unsigned long long m0 = __ballot(v0 <= thr);
        unsigned long long m1 = __ballot(v1 <= thr);
        unsigned long long m2 = __ballot(v2 <= thr);
        unsigned long long m3 = __ballot(v3 <= thr);

        const float* xl = sAf + lr * DIM;    // this row's x, in LDS
        float4 xv[8];
        {
            const float4* xq4 = (const float4*)(xl + kp * 32);
            #pragma unroll
            for (int j2 = 0; j2 < 8; ++j2) xv[j2] = xq4[j2];
        }

        float bv = 3.0e38f;
        int   bi = 0x7fffffff;

        // (b) paired candidate eval: 2 peels per pass, loads issued together
        while (m0 | m1 | m2 | m3) {
            int ga, gb;
            PEEL(ga); PEEL(gb);
            const int ca = ga * 16 + cig;
            const float4* wqa = (const float4*)(W + (size_t)ca * DIM + kp * 32);
            if (gb >= 0) {
                const int cb2 = gb * 16 + cig;
                const float4* wqb = (const float4*)(W + (size_t)cb2 * DIM + kp * 32);
                float4 wa[8], wb[8];
                #pragma unroll
                for (int j2 = 0; j2 < 8; ++j2) { wa[j2] = wqa[j2]; wb[j2] = wqb[j2]; }
                float da = 0.f, db = 0.f;
                #pragma unroll
                for (int j2 = 0; j2 < 8; ++j2) {
                    da = fmaf(xv[j2].x, wa[j2].x, da);
                    db = fmaf(xv[j2].x, wb[j2].x, db);
                    da = fmaf(xv[j2].y, wa[j2].y, da);
                    db = fmaf(xv[j2].y, wb[j2].y, db);
                    da = fmaf(xv[j2].z, wa[j2].z, da);
                    db = fmaf(xv[j2].z, wb[j2].z, db);
                    da = fmaf(xv[j2].w, wa[j2].w, da);
                    db = fmaf(xv[j2].w, wb[j2].w, db);
                }
                float oa = __shfl_xor(da, 1, 64); da = __fadd_rn(da, oa);
                float ob = __shfl_xor(db, 1, 64); db = __fadd_rn(db, ob);
                oa = __shfl_xor(da, 2, 64); da = __fadd_rn(da, oa);
                ob = __shfl_xor(db, 2, 64); db = __fadd_rn(db, ob);
                const float dA = __fsub_rn(__fadd_rn(sxr[t], ssw[ca]),  __fmul_rn(2.0f, da));
                const float dB = __fsub_rn(__fadd_rn(sxr[t], ssw[cb2]), __fmul_rn(2.0f, db));
                if (dA < bv || (dA == bv && ca  < bi)) { bv = dA; bi = ca; }
                if (dB < bv || (dB == bv && cb2 < bi)) { bv = dB; bi = cb2; }
            } else {
                float4 wa[8];
                #pragma unroll
                for (int j2 = 0; j2 < 8; ++j2) wa[j2] = wqa[j2];
                float da = 0.f;
                #pragma unroll
                for (int j2 = 0; j2 < 8; ++j2) {
                    da = fmaf(xv[j2].x, wa[j2].x, da);
                    da = fmaf(xv[j2].y, wa[j2].y, da);
                    da = fmaf(xv[j2].z, wa[j2].z, da);
                    da = fmaf(xv[j2].w, wa[j2].w, da);
                }
                float oa = __shfl_xor(da, 1, 64); da = __fadd_rn(da, oa);
                oa = __shfl_xor(da, 2, 64); da = __fadd_rn(da, oa);
                const float dA = __fsub_rn(__fadd_rn(sxr[t], ssw[ca]), __fmul_rn(2.0f, da));
                if (dA < bv || (dA == bv && ca < bi)) { bv = dA; bi = ca; }
            }
        }

        // per-row argmin + gather + stores (R12 form -- R11's batching regressed)
        #pragma unroll
        for (int off = 1; off < 64; off <<= 1) {
            const float ov = __shfl_xor(bv, off, 64);
            const int   oi = __shfl_xor(bi, off, 64);
            if (ov < bv || (ov == bv && oi < bi)) { bv = ov; bi = oi; }
        }

        const float2 wv2 = *(const float2*)(W + (size_t)bi * DIM + lane * 2);
        const float2 xv2 = *(const float2*)(xl + lane * 2);
        const float d0 = wv2.x - xv2.x, d1 = wv2.y - xv2.y;
        const float p = fmaf(d0, d0, d1 * d1);
        *(float2*)(out0 + (size_t)row * DIM + lane * 2) = wv2;
        *(float2*)(out1 + (size_t)row * DIM + lane * 2) = wv2;
        p_acc = __fadd_rn(p_acc, p);
        if (lane == 0) out_idx[row] = (float)bi;
    }
    // wave partial -> block partial -> global double accumulate (loss)
    #pragma unroll
    for (int off = 32; off > 0; off >>= 1) p_acc += __shfl_down(p_acc, off, 64);
    if (lane == 0) red16[wv] = p_acc;
    __syncthreads();
    if (tid < 16) {
        float sblk = red16[tid];
        sblk += __shfl_xor(sblk, 1, 64);
        sblk += __shfl_xor(sblk, 2, 64);
        sblk += __shfl_xor(sblk, 4, 64);
        sblk += __shfl_xor(sblk, 8, 64);
        if (tid == 0) {
            atomicAdd(dsum, (double)sblk);
            __threadfence();
            const int prev = atomicAdd(cnt, 1);
            if (prev == (int)gridDim.x - 1) {
                __threadfence();
                const double tot = atomicAdd(dsum, 0.0);   // read full sum
                out_loss[0] = (float)(tot * (1.25 / ((double)NROWS * (double)DIM)));
            }
        }
    }
}

extern "C" void kernel_launch(void* const* d_in, const int* in_sizes, int n_in,
                              void* d_out, int out_size, void* d_ws, size_t ws_size,
                              hipStream_t stream) {
    const float* x = (const float*)d_in[0];   // [32768,128]
    const float* W = (const float*)d_in[1];   // [4096,128]
    float* out = (float*)d_out;

    float* out_q2d  = out;
    float* out_qst  = out + (size_t)NROWS * DIM;
    float* out_loss = out + (size_t)2 * NROWS * DIM;
    float* out_idx  = out + (size_t)2 * NROWS * DIM + 1;

    // ws layout (floats): sww[0..4096) | dsum@4096 cnt@4098 | swwh@8192 (8KB) | Wh2@36864
    float* ws   = (float*)d_ws;
    float* sww  = ws;
    double* dsum = (double*)(ws + 4096);                // byte 16384, 8-aligned
    int*    cnt  = (int*)(ws + 4098);
    _Float16* swwh = (_Float16*)(ws + 8192);            // 4096 halfs
    _Float16* Wh2  = (_Float16*)(ws + 4096 + 32768);    // 4096*128 fp16, fragment-major

    k_prep<<<NEMB / 8, 256, 0, stream>>>(W, Wh2, sww, swwh, dsum, cnt);
    k_main<<<NROWS / RPB, 1024, 0, stream>>>(x, Wh2, W, sww, swwh,
                                             out_q2d, out_qst, out_idx,
                                             dsum, cnt, out_loss);
}

// Round 15
// 145.066 us; speedup vs baseline: 2.0319x; 2.0319x over previous
//
#include <hip/hip_runtime.h>
#include <hip/hip_bf16.h>

#define NEMB  4096
#define DIM   128
#define NROWS 32768
#define MARGIN 3.5e-4f   // >= 5x approx-error bound; validated r5-r8 (+1e-9 fold term)
#define RPB   128        // rows per block -> grid 256 = 1 block/CU
#define CHUNK 128        // codes per K-loop iteration
#define NITER 32         // NEMB/CHUNK

typedef _Float16 half8  __attribute__((ext_vector_type(8)));
typedef _Float16 half4v __attribute__((ext_vector_type(4)));
typedef _Float16 half2v __attribute__((ext_vector_type(2)));
typedef float    float16v __attribute__((ext_vector_type(16)));

typedef const __attribute__((address_space(1))) void* gas_ptr;
typedef __attribute__((address_space(3))) void*       las_ptr;

__device__ __forceinline__ void gload16(const void* g, void* l) {
    __builtin_amdgcn_global_load_lds((gas_ptr)g, (las_ptr)l, 16, 0, 0);
}

__device__ __forceinline__ half2v hmin2(half2v a, half2v b) {
    half2v r;
    r.x = (a.x < b.x) ? a.x : b.x;
    r.y = (a.y < b.y) ? a.y : b.y;
    return r;
}

// ---------------- K1: W -> fp16 fragment-major + ||w||^2 + swwh + Wp (R23) ----
// Wp layout (fp32, 2MB): float4 index g*512 + j2*64 + lane, lane = cig*4+kp,
// holding W[g*16+cig][kp*32+j2*4 .. +3].  Pure permutation of W -> refine's
// candidate loads become 1KB-contiguous (16 lines/instr vs 64).  Bit-identical
// values.  Wp may be NULL (workspace too small) -> k_main falls back to W.
__launch_bounds__(256)
__global__ void k_prep(const float* __restrict__ W, _Float16* __restrict__ Wh2,
                       float* __restrict__ sww, _Float16* __restrict__ swwh,
                       float* __restrict__ Wp,
                       double* __restrict__ dsum, int* __restrict__ cnt) {
    const int b = blockIdx.x;               // 512 blocks, 8 rows each
    const int t = threadIdx.x;
    const int rbase = b * 8;

    if (b == 0 && t == 0) { *dsum = 0.0; *cnt = 0; }   // loss accumulators

    const int i4 = rbase * 32 + t;
    const float4 v = ((const float4*)W)[i4];
    const int r  = i4 >> 5;
    const int m  = i4 & 31;                 // float4 index within the row
    const int k0 = m * 4;
    const int s  = r >> 5, cs = r & 31, c = k0 >> 4, h2 = (k0 >> 3) & 1, j0 = k0 & 7;
    half4v hv = { (_Float16)(v.x * 65536.0f), (_Float16)(v.y * 65536.0f),
                  (_Float16)(v.z * 65536.0f), (_Float16)(v.w * 65536.0f) };
    *(half4v*)(Wh2 + (s * 8 + c) * 512 + (h2 * 32 + cs) * 8 + j0) = hv;

    // Wp permutation store: g=r>>4, cig=r&15, kp=m>>3, j2=m&7
    if (Wp) {
        ((float4*)Wp)[(r >> 4) * 512 + (m & 7) * 64 + (r & 15) * 4 + (m >> 3)] = v;
    }

    if (t < 64) {   // numpy-pairwise ||w||^2 (exact fp32 semantics, validated r3-r8)
        const int row = rbase + (t >> 3);
        const int j   = t & 7;
        const float* p = W + (size_t)row * DIM + j;
        float vv = p[0];
        float rr = __fmul_rn(vv, vv);
        #pragma unroll
        for (int q = 1; q < 16; ++q) { vv = p[q * 8]; rr = __fadd_rn(rr, __fmul_rn(vv, vv)); }
        float o = __shfl_xor(rr, 1, 64); rr = __fadd_rn(rr, o);
        o = __shfl_xor(rr, 2, 64); rr = __fadd_rn(rr, o);
        o = __shfl_xor(rr, 4, 64); rr = __fadd_rn(rr, o);
        if (j == 0) {
            sww[row]  = rr;
            swwh[row] = (_Float16)(rr * 32768.0f);   // sww*2^15, |err| ~ sww*2^-11
        }
    }
}

// ---------------- K2: R12 scan/staging/refine + Wp coalesced candidate loads ----
// Only change vs R12 (110.5us): the refine item eval reads the W quarter from Wp
// (1KB contiguous per load instr, 16 lines vs 64 -> 4x fewer L1 line-transactions
// on refine's dominant measured cost).  Same values, same fmaf order ->
// bit-identical outputs.  Falls back to W when Wp==NULL.
__global__ __launch_bounds__(1024, 4)
void k_main(const float* __restrict__ x, const _Float16* __restrict__ Wh2,
            const float* __restrict__ W, const float* __restrict__ sww,
            const _Float16* __restrict__ swwh, const float* __restrict__ Wp,
            float* __restrict__ out0, float* __restrict__ out1,
            float* __restrict__ out_idx, double* __restrict__ dsum,
            int* __restrict__ cnt, float* __restrict__ out_loss) {
    __shared__ __align__(16) _Float16 sA[2 * CHUNK * DIM];   // 64 KB dbuf / x-cache
    __shared__ _Float16 gbuf[RPB * 256];       // 64 KB group minima (swizzled)
    __shared__ float ssw[NEMB];                // 16 KB sww copy (refine only)
    __shared__ _Float16 swwh_lds[NEMB];        // 8 KB sww*2^15 fp16 (scan fold)
    __shared__ float red16[16];                // block loss partials

    const int tid  = threadIdx.x;
    const int wv   = tid >> 6;      // 0..15
    const int lane = tid & 63;
    const int l31  = lane & 31;
    const int h    = lane >> 5;
    const int r0   = blockIdx.x * RPB;
    const int mt   = wv & 3;        // 32-code slab within chunk
    const int np   = wv >> 2;       // ntile 0..3 (rows np*32..np*32+31)

    // prologue DMA first: chunk `start` -> buffer 0; latency hides under staging
    const int start = (blockIdx.x >> 3) & 31;
    {
        const char* src = (const char*)Wh2 + (size_t)start * (CHUNK * DIM * 2);
        #pragma unroll
        for (int r = 0; r < 2; ++r)
            gload16(src + wv * 2048 + r * 1024 + lane * 16, (char*)sA + wv * 2048 + r * 1024);
    }

    ((float4*)ssw)[tid] = ((const float4*)sww)[tid];
    if (tid < 512) ((float4*)swwh_lds)[tid] = ((const float4*)swwh)[tid];

    // B fragments: x rows of ntile np -> fp16 regs, B[n=lane&31][k=h*8+j] per 16-k chunk
    half8 bfr[8];
    {
        const float* xr = x + (size_t)(r0 + np * 32 + l31) * DIM + h * 8;
        #pragma unroll
        for (int c = 0; c < 8; ++c) {
            const float4 u0 = *(const float4*)(xr + c * 16);
            const float4 u1 = *(const float4*)(xr + c * 16 + 4);
            bfr[c] = (half8){ (_Float16)u0.x, (_Float16)u0.y, (_Float16)u0.z, (_Float16)u0.w,
                              (_Float16)u1.x, (_Float16)u1.y, (_Float16)u1.z, (_Float16)u1.w };
        }
    }

    // B_extra: B[row][k=0] = -1  (k=0 lives at h==0, j==0)
    half8 bx2 = (_Float16)0.0f;
    if (h == 0) bx2[0] = (_Float16)-1.0f;

    // loop-invariant zero accumulator (C operand of the first MFMA)
    float16v zero16;
    #pragma unroll
    for (int i = 0; i < 16; ++i) zero16[i] = 0.f;

    // ax: high regs zeroed once; only element 0 rewritten per iteration
    half8 ax = (_Float16)0.0f;

    // sxx (numpy-pairwise exact) for this wave's 8 refine rows, kept in regs
    float sxx_reg;
    {
        const float* ps = x + (size_t)(r0 + wv * 8 + (lane >> 3)) * DIM + (lane & 7);
        float vv = ps[0];
        float rr = __fmul_rn(vv, vv);
        #pragma unroll
        for (int q = 1; q < 16; ++q) { vv = ps[q * 8]; rr = __fadd_rn(rr, __fmul_rn(vv, vv)); }
        float o = __shfl_xor(rr, 1, 64); rr = __fadd_rn(rr, o);
        o = __shfl_xor(rr, 2, 64); rr = __fadd_rn(rr, o);
        o = __shfl_xor(rr, 4, 64); rr = __fadd_rn(rr, o);
        sxx_reg = rr;
    }

    for (int it = 0; it < NITER; ++it) {
        __syncthreads();   // drains DMA issued one full iteration ago
        if (it + 1 < NITER) {
            const int nc = (start + it + 1) & (NITER - 1);
            const char* src = (const char*)Wh2 + (size_t)nc * (CHUNK * DIM * 2);
            char* dst = (char*)sA + ((it + 1) & 1) * (CHUNK * DIM * 2);
            #pragma unroll
            for (int r = 0; r < 2; ++r)
                gload16(src + wv * 2048 + r * 1024 + lane * 16, dst + wv * 2048 + r * 1024);
        }
        const int cb = (start + it) & (NITER - 1);
        const int s  = cb * 4 + mt;   // global 32-code slab [0,128)

        // A_extra elem 0: swwh[code] on h==0 lanes (other 7 halfs stay 0)
        ax[0] = (h == 0) ? swwh_lds[s * 32 + l31] : (_Float16)0.0f;

        const _Float16* curb = sA + (it & 1) * (CHUNK * DIM);

        // first MFMA consumes zero16 as C (no acc re-init), then accumulate
        float16v acc;
        {
            const half8 a0 = *(const half8*)(curb + (mt * 8 + 0) * 512 + lane * 8);
            acc = __builtin_amdgcn_mfma_f32_32x32x16_f16(a0, bfr[0], zero16, 0, 0, 0);
        }
        #pragma unroll
        for (int c = 1; c < 8; ++c) {
            const half8 a = *(const half8*)(curb + (mt * 8 + c) * 512 + lane * 8);
            acc = __builtin_amdgcn_mfma_f32_32x32x16_f16(a, bfr[c], acc, 0, 0, 0);
        }
        // 9th MFMA: acc' = 2^16 x.w - 2^15 sww
        acc = __builtin_amdgcn_mfma_f32_32x32x16_f16(ax, bx2, acc, 0, 0, 0);

        // epilogue: group min = -2^-15 * max(acc'); max exact, scale exact
        const float mx0 = fmaxf(fmaxf(fmaxf(acc[0], acc[1]), fmaxf(acc[2], acc[3])),
                                fmaxf(fmaxf(acc[4], acc[5]), fmaxf(acc[6], acc[7])));
        const float mx1 = fmaxf(fmaxf(fmaxf(acc[8], acc[9]), fmaxf(acc[10], acc[11])),
                                fmaxf(fmaxf(acc[12], acc[13]), fmaxf(acc[14], acc[15])));
        const float g0 = mx0 * -0x1p-15f;
        const float g1 = mx1 * -0x1p-15f;
        union { half2v h2; int u; } cu, ot;
        cu.h2.x = (_Float16)g0; cu.h2.y = (_Float16)g1;   // groups 2s, 2s+1
        ot.u = __shfl_xor(cu.u, 32, 64);
        cu.h2 = hmin2(cu.h2, ot.h2);
        if (h == 0) {
            const int row = np * 32 + l31;                // local row
            const int ws  = (s + row) & 127;              // swizzled word slot
            ((int*)gbuf)[row * 128 + ws] = cu.u;
        }
    }

    __syncthreads();   // scan complete; sA (DMA buffer) now dead

    // ---- refill sA with the block's x rows (64 KB fp32, coalesced) ----
    {
        float4* sAf4 = (float4*)sA;
        const float4* xg4 = (const float4*)(x + (size_t)r0 * DIM);
        #pragma unroll
        for (int i = 0; i < 4; ++i) sAf4[tid + i * 1024] = xg4[tid + i * 1024];
    }
    __syncthreads();
    const float* sAf = (const float*)sA;

    // ---- fused flag + exact refine (R12 form; candidate W from Wp if present) ----
    const int cig = lane >> 2;
    const int kp  = lane & 3;
    const float4* Wp4 = (const float4*)Wp;   // may be NULL
    float p_acc = 0.f;
    for (int t = 0; t < 8; ++t) {
        const int lr  = wv * 8 + t;
        const int row = r0 + lr;

        const int2 gw = *(const int2*)((const char*)gbuf + lr * 512 + lane * 8);
        union { half2v h2; int u; } pa, pb;
        pa.u = gw.x; pb.u = gw.y;
        const float v0 = (float)pa.h2.x, v1 = (float)pa.h2.y;
        const float v2 = (float)pb.h2.x, v3 = (float)pb.h2.y;
        float m = fminf(fminf(v0, v1), fminf(v2, v3));
        #pragma unroll
        for (int off = 1; off < 64; off <<= 1) m = fminf(m, __shfl_xor(m, off, 64));
        const float thr = m + MARGIN;
        unsigned long long bal[4];
        bal[0] = __ballot(v0 <= thr);
        bal[1] = __ballot(v1 <= thr);
        bal[2] = __ballot(v2 <= thr);
        bal[3] = __ballot(v3 <= thr);

        const float sxr = __shfl(sxx_reg, t * 8, 64);
        const float* xl = sAf + lr * DIM;    // this row's x, in LDS

        // hoisted x quarter (from LDS; 16-lane same-address -> broadcast)
        float4 xv[8];
        {
            const float4* xq4 = (const float4*)(xl + kp * 32);
            #pragma unroll
            for (int j2 = 0; j2 < 8; ++j2) xv[j2] = xq4[j2];
        }

        float bv = 3.0e38f;
        int   bi = 0x7fffffff;

        #pragma unroll
        for (int j = 0; j < 4; ++j) {
            unsigned long long msk = bal[j];
            while (msk) {
                const int l = __builtin_ctzll(msk);
                msk &= msk - 1;
                const int wsl = 2 * l + (j >> 1);
                const int g   = 2 * ((wsl - lr) & 127) + (j & 1);
                const int c   = g * 16 + cig;
                float dot = 0.f;
                if (Wp4) {
                    // coalesced: per j2, 64 lanes read 1KB contiguous (16 lines)
                    const float4* wq4 = Wp4 + g * 512 + lane;
                    #pragma unroll
                    for (int j2 = 0; j2 < 8; ++j2) {
                        const float4 wv4 = wq4[j2 * 64];
                        dot = fmaf(xv[j2].x, wv4.x, dot);
                        dot = fmaf(xv[j2].y, wv4.y, dot);
                        dot = fmaf(xv[j2].z, wv4.z, dot);
                        dot = fmaf(xv[j2].w, wv4.w, dot);
                    }
                } else {
                    const float4* wq4 = (const float4*)(W + (size_t)c * DIM + kp * 32);
                    #pragma unroll
                    for (int j2 = 0; j2 < 8; ++j2) {
                        const float4 wv4 = wq4[j2];
                        dot = fmaf(xv[j2].x, wv4.x, dot);
                        dot = fmaf(xv[j2].y, wv4.y, dot);
                        dot = fmaf(xv[j2].z, wv4.z, dot);
                        dot = fmaf(xv[j2].w, wv4.w, dot);
                    }
                }
                float o = __shfl_xor(dot, 1, 64); dot = __fadd_rn(dot, o);
                o = __shfl_xor(dot, 2, 64); dot = __fadd_rn(dot, o);
                const float A = __fadd_rn(sxr, ssw[c]);
                const float d = __fsub_rn(A, __fmul_rn(2.0f, dot));
                if (d < bv || (d == bv && c < bi)) { bv = d; bi = c; }
            }
        }
        #pragma unroll
        for (int off = 1; off < 64; off <<= 1) {
            const float ov = __shfl_xor(bv, off, 64);
            const int   oi = __shfl_xor(bi, off, 64);
            if (ov < bv || (ov == bv && oi < bi)) { bv = ov; bi = oi; }
        }

        const float2 wv2 = *(const float2*)(W + (size_t)bi * DIM + lane * 2);
        const float2 xv2 = *(const float2*)(xl + lane * 2);
        const float d0 = wv2.x - xv2.x, d1 = wv2.y - xv2.y;
        const float p = fmaf(d0, d0, d1 * d1);
        *(float2*)(out0 + (size_t)row * DIM + lane * 2) = wv2;
        *(float2*)(out1 + (size_t)row * DIM + lane * 2) = wv2;
        p_acc = __fadd_rn(p_acc, p);
        if (lane == 0) out_idx[row] = (float)bi;
    }
    // wave partial -> block partial -> global double accumulate (loss)
    #pragma unroll
    for (int off = 32; off > 0; off >>= 1) p_acc += __shfl_down(p_acc, off, 64);
    if (lane == 0) red16[wv] = p_acc;
    __syncthreads();
    if (tid < 16) {
        float sblk = red16[tid];
        sblk += __shfl_xor(sblk, 1, 64);
        sblk += __shfl_xor(sblk, 2, 64);
        sblk += __shfl_xor(sblk, 4, 64);
        sblk += __shfl_xor(sblk, 8, 64);
        if (tid == 0) {
            atomicAdd(dsum, (double)sblk);
            __threadfence();
            const int prev = atomicAdd(cnt, 1);
            if (prev == (int)gridDim.x - 1) {
                __threadfence();
                const double tot = atomicAdd(dsum, 0.0);   // read full sum
                out_loss[0] = (float)(tot * (1.25 / ((double)NROWS * (double)DIM)));
            }
        }
    }
}

extern "C" void kernel_launch(void* const* d_in, const int* in_sizes, int n_in,
                              void* d_out, int out_size, void* d_ws, size_t ws_size,
                              hipStream_t stream) {
    const float* x = (const float*)d_in[0];   // [32768,128]
    const float* W = (const float*)d_in[1];   // [4096,128]
    float* out = (float*)d_out;

    float* out_q2d  = out;
    float* out_qst  = out + (size_t)NROWS * DIM;
    float* out_loss = out + (size_t)2 * NROWS * DIM;
    float* out_idx  = out + (size_t)2 * NROWS * DIM + 1;

    // ws layout (floats): sww[0..4096) | dsum@4096 cnt@4098 | swwh@8192 (8KB) |
    //                     Wh2@36864 (1MB fp16) | Wp@299008 (2MB fp32, optional)
    float* ws   = (float*)d_ws;
    float* sww  = ws;
    double* dsum = (double*)(ws + 4096);                // byte 16384, 8-aligned
    int*    cnt  = (int*)(ws + 4098);
    _Float16* swwh = (_Float16*)(ws + 8192);            // 4096 halfs
    _Float16* Wh2  = (_Float16*)(ws + 4096 + 32768);    // 4096*128 fp16, fragment-major

    const size_t wp_off_f = 299008;                     // floats (after Wh2)
    const size_t need_b   = (wp_off_f + (size_t)NEMB * DIM) * 4;
    float* Wp = (ws_size >= need_b) ? (ws + wp_off_f) : (float*)nullptr;

    k_prep<<<NEMB / 8, 256, 0, stream>>>(W, Wh2, sww, swwh, Wp, dsum, cnt);
    k_main<<<NROWS / RPB, 1024, 0, stream>>>(x, Wh2, W, sww, swwh, Wp,
                                             out_q2d, out_qst, out_idx,
                                             dsum, cnt, out_loss);
}